// Round 15
// baseline (248.713 us; speedup 1.0000x reference)
//
#include <hip/hip_runtime.h>
#include <math.h>

#define BB 4096
#define DD 1024
#define KK 5
#define PP 1323
#define PTS 7          // points per ptile; 1323 = 189 * 7
#define NPT 189        // p-tiles
#define BLK 256

// (2*pi)^(-3/2)
#define INV_2PI_POW15 0.06349363593424097f

// ---- head config (R13-proven head_body) ----
#define GR   16        // rows per head block -> 256 head blocks
#define RST  13        // s_red inner stride (12 + 1)
#define CSTR 49        // s_c inner stride
#define NG   13        // param groups of 4
#define WPKN 49152     // packed weight elements

#define MAGIC 0x5CA1AB1Eu

typedef short  bf16x8 __attribute__((ext_vector_type(8)));
typedef float  f32x4  __attribute__((ext_vector_type(4)));

__device__ __forceinline__ short f2bf(float f) {
    union { float f; unsigned u; } x; x.f = f;
    const unsigned r = x.u + 0x7fffu + ((x.u >> 16) & 1u);  // RNE
    return (short)(r >> 16);
}
__device__ __forceinline__ float softplus_f(float x) {
    return (x > 20.f) ? x : log1pf(expf(x));
}

__device__ __forceinline__ int wpk_index(int k, int j) {
    // Wpk[chunk][nt][lane][8]: k = chunk*32 + (lane>>4)*8 + ee, j = nt*16 + (lane&15)
    const int chunk = k >> 5;
    const int kin   = k & 31;
    const int lane  = ((kin >> 3) << 4) | (j & 15);
    const int nt    = j >> 4;
    const int ee    = k & 7;
    return ((chunk * 3 + nt) * 64 + lane) * 8 + ee;
}

// ---------------------------------------------------------------------------
// Kernel 0: pack weights -> bf16 MFMA fragment order, coalesced reads.
// ---------------------------------------------------------------------------
__global__ __launch_bounds__(256) void pack_kernel(
    const float* __restrict__ Wmix,
    const float* __restrict__ Wmean,
    const float* __restrict__ Wscale,
    short* __restrict__ Wpk)
{
    const int e = blockIdx.x * 256 + threadIdx.x;   // 0 .. 49151
    int k, j; float v;
    if (e < 5120) {                       // Wmix: [1024][5]
        k = e / 5;  j = e - k * 5;
        v = Wmix[e];
    } else if (e < 17408) {               // Wmean: [1024][12]
        const int i = e - 5120;
        k = i / 12; j = 5 + (i - k * 12);
        v = Wmean[i];
    } else if (e < 48128) {               // Wscale: [1024][30]
        const int i = e - 17408;
        k = i / 30; j = 17 + (i - k * 30);
        v = Wscale[i];
    } else {                              // zero-fill j = 47
        k = e - 48128; j = 47; v = 0.f;
    }
    Wpk[wpk_index(k, j)] = f2bf(v);
}

// ---------------------------------------------------------------------------
// head block body (R13-verified): 256 threads, 4 waves, wave w = k-quarter.
// ---------------------------------------------------------------------------
__device__ __forceinline__ void head_body(int hb, int t,
    const float* __restrict__ rep, const short* __restrict__ Wpk,
    const float* __restrict__ bmix, const float* __restrict__ bmean,
    const float* __restrict__ bscale,
    float* __restrict__ Lout, float* __restrict__ par4,
    float (*s_red)[64][RST], float (*s_c)[CSTR], float (*s_L)[KK][6])
{
    const int w  = t >> 6;          // wave 0..3
    const int l  = t & 63;
    const int lm = l & 15;
    const int lk = (l >> 4) * 8;
    const int b0 = hb * GR;

    f32x4 acc[3] = {f32x4{0,0,0,0}, f32x4{0,0,0,0}, f32x4{0,0,0,0}};

#pragma unroll
    for (int kt = 0; kt < 8; ++kt) {
        const int chunk = w * 8 + kt;        // global 32-k chunk 0..31
        const int kof   = chunk * 32 + lk;

        const float* arow = rep + (size_t)(b0 + lm) * DD + kof;
        const f32x4 a0 = *(const f32x4*)(arow);
        const f32x4 a1 = *(const f32x4*)(arow + 4);

        bf16x8 ah;
#pragma unroll
        for (int u = 0; u < 4; ++u) {
            ah[u]     = f2bf(a0[u]);
            ah[u + 4] = f2bf(a1[u]);
        }

#pragma unroll
        for (int nt = 0; nt < 3; ++nt) {
            const bf16x8 bh = *(const bf16x8*)(Wpk + (((size_t)chunk * 3 + nt) * 64 + l) * 8);
            acc[nt] = __builtin_amdgcn_mfma_f32_16x16x32_bf16(ah, bh, acc[nt], 0, 0, 0);
        }
    }

#pragma unroll
    for (int nt = 0; nt < 3; ++nt)
#pragma unroll
        for (int r = 0; r < 4; ++r)
            s_red[w][l][nt * 4 + r] = acc[nt][r];
    __syncthreads();

    // cooperative sum into s_c[b_loc][j]; C layout [m89]
    for (int e = t; e < GR * 47; e += BLK) {
        const int b_loc = e & 15;
        const int j     = e >> 4;
        const int lane  = ((b_loc >> 2) << 4) | (j & 15);
        const int reg   = ((j >> 4) << 2) | (b_loc & 3);
        s_c[b_loc][j] = s_red[0][lane][reg] + s_red[1][lane][reg]
                      + s_red[2][lane][reg] + s_red[3][lane][reg];
    }
    __syncthreads();

    if (t < GR * KK) {
        const int k     = t >> 4;
        const int b_loc = t & 15;
        const int b     = b0 + b_loc;

        float logits[KK];
#pragma unroll
        for (int kk = 0; kk < KK; ++kk) logits[kk] = s_c[b_loc][kk] + bmix[kk];

        float m[3];
#pragma unroll
        for (int c = 0; c < 3; ++c)
            m[c] = (k > 0) ? (s_c[b_loc][5 + (k - 1) * 3 + c] + bmean[(k - 1) * 3 + c]) : 0.f;

        float sc[6];
#pragma unroll
        for (int c = 0; c < 6; ++c)
            sc[c] = s_c[b_loc][17 + k * 6 + c] + bscale[k * 6 + c];

        float mx = logits[0];
#pragma unroll
        for (int kk = 1; kk < KK; ++kk) mx = fmaxf(mx, logits[kk]);
        float den = 0.f;
#pragma unroll
        for (int kk = 0; kk < KK; ++kk) den += expf(logits[kk] - mx);
        const float wgt = expf(logits[k] - mx) / den;

        const float L00 = softplus_f(sc[0]);
        const float L10 = sc[1];
        const float L11 = softplus_f(sc[2]);
        const float L20 = sc[3];
        const float L21 = sc[4];
        const float L22 = softplus_f(sc[5]);

        const float r00 = 1.f / L00;
        const float r11 = 1.f / L11;
        const float r22 = 1.f / L22;
        const float a   = wgt * r00 * r11 * r22 * INV_2PI_POW15;

        s_L[b_loc][k][0] = L00;
        s_L[b_loc][k][1] = L10;
        s_L[b_loc][k][2] = L11;
        s_L[b_loc][k][3] = L20;
        s_L[b_loc][k][4] = L21;
        s_L[b_loc][k][5] = L22;

        float pv[10] = { m[0], m[1], m[2], r00, L10, r11, L20, L21, r22, a };
#pragma unroll
        for (int i = 0; i < 10; ++i) {
            const int q = k * 10 + i;
            par4[(((size_t)(q >> 2)) * BB + b) * 4 + (q & 3)] = pv[i];
        }
    }
    __syncthreads();

    // coalesced Lout write (720 contiguous floats)
    for (int e = t; e < GR * KK * 9; e += BLK) {
        const int b_loc = e / 45;
        const int rem   = e - b_loc * 45;
        const int k     = rem / 9;
        const int e9    = rem - k * 9;
        const int rr    = e9 / 3;
        const int cc    = e9 - rr * 3;
        const float v = (cc > rr) ? 0.f : s_L[b_loc][k][(rr * (rr + 1)) / 2 + cc];
        Lout[(size_t)b0 * 45 + e] = v;
    }
}

// ---------------------------------------------------------------------------
// Mega kernel: 1024 blocks x 256 thr, all co-resident (4 blocks/CU).
// Blocks 0..255: head for rows [16g, 16g+16), then sentinel-flag release.
// All blocks: eval for b-tile (g&15), after acquiring that tile's 16 flags.
// Sentinel flags (not counters) make poisoned-ws replays wait correctly and
// steady-state replays skip the wait (par4 values are replay-invariant).
// ---------------------------------------------------------------------------
__global__ __launch_bounds__(BLK, 4) void mega_kernel(
    const float* __restrict__ rep,
    const float* __restrict__ dxyz,
    const short* __restrict__ Wpk,
    const float* __restrict__ bmix,
    const float* __restrict__ bmean,
    const float* __restrict__ bscale,
    float* __restrict__ out,
    float* __restrict__ Lout,
    float* __restrict__ par4,
    unsigned int* __restrict__ flags)
{
    __shared__ float s_red[4][64][RST];     // 13.3 KB
    __shared__ float s_c[GR][CSTR];         // 3.1 KB
    __shared__ float s_L[GR][KK][6];        // 1.9 KB

    const int t = threadIdx.x;
    const int g = blockIdx.x;

    // ---- producer phase: head (blocks 0..255) ----
    if (g < BB / GR) {
        head_body(g, t, rep, Wpk, bmix, bmean, bscale, Lout, par4,
                  s_red, s_c, s_L);
        __threadfence();                 // device-scope: par4 visible
        __syncthreads();                 // all threads' stores fenced
        if (t == 0)
            __hip_atomic_store(&flags[g], MAGIC, __ATOMIC_RELEASE,
                               __HIP_MEMORY_SCOPE_AGENT);
    }

    // ---- consumer phase: eval for b-tile g&15 ----
    const int bt = g & 15;
    if (t == 0) {
#pragma unroll 1
        for (int hb = bt * 16; hb < bt * 16 + 16; ++hb) {
            while (__hip_atomic_load(&flags[hb], __ATOMIC_ACQUIRE,
                                     __HIP_MEMORY_SCOPE_AGENT) != MAGIC)
                __builtin_amdgcn_s_sleep(16);
        }
    }
    __syncthreads();
    __threadfence();                     // belt-and-braces cache sync

    const int b = bt * BLK + t;

    float pr[NG * 4];
#pragma unroll
    for (int gg = 0; gg < NG; ++gg) {
        const f32x4 v = *(const f32x4*)(par4 + ((size_t)gg * BB + b) * 4);
        pr[gg * 4 + 0] = v[0];
        pr[gg * 4 + 1] = v[1];
        pr[gg * 4 + 2] = v[2];
        pr[gg * 4 + 3] = v[3];
    }

    for (int pt = g >> 4; pt < NPT; pt += 64) {
        const int p0 = pt * PTS;
#pragma unroll
        for (int i = 0; i < PTS; ++i) {
            const size_t idx = (size_t)(p0 + i) * BB + b;
            const float* xv = dxyz + idx * 3;
            const float x0 = xv[0];
            const float x1 = xv[1];
            const float x2 = xv[2];

            float res = 0.f;
#pragma unroll
            for (int k = 0; k < KK; ++k) {
                const float d0 = x0 - pr[k * 10 + 0];
                const float d1 = x1 - pr[k * 10 + 1];
                const float d2 = x2 - pr[k * 10 + 2];
                const float z0 = d0 * pr[k * 10 + 3];
                const float z1 = fmaf(-pr[k * 10 + 4], z0, d1) * pr[k * 10 + 5];
                const float z2 = fmaf(-pr[k * 10 + 7], z1, fmaf(-pr[k * 10 + 6], z0, d2)) * pr[k * 10 + 8];
                const float q  = fmaf(z2, z2, fmaf(z1, z1, z0 * z0));
                res = fmaf(pr[k * 10 + 9], __expf(-0.5f * q), res);
            }
            out[idx] = res;
        }
    }
}

extern "C" void kernel_launch(void* const* d_in, const int* in_sizes, int n_in,
                              void* d_out, int out_size, void* d_ws, size_t ws_size,
                              hipStream_t stream) {
    const float* rep    = (const float*)d_in[0];
    const float* dxyz   = (const float*)d_in[1];
    const float* Wmix   = (const float*)d_in[2];
    const float* bmix   = (const float*)d_in[3];
    const float* Wmean  = (const float*)d_in[4];
    const float* bmean  = (const float*)d_in[5];
    const float* Wscale = (const float*)d_in[6];
    const float* bscale = (const float*)d_in[7];

    float* out  = (float*)d_out;
    float* Lout = out + (size_t)BB * PP;          // second tuple output

    float*        par4  = (float*)d_ws;                        // 852 KB
    short*        Wpk   = (short*)(par4 + (size_t)NG * BB * 4); // 98 KB
    unsigned int* flags = (unsigned int*)(Wpk + WPKN);          // 1 KB

    pack_kernel<<<192, 256, 0, stream>>>(Wmix, Wmean, Wscale, Wpk);

    mega_kernel<<<1024, BLK, 0, stream>>>(rep, dxyz, Wpk, bmix, bmean, bscale,
                                          out, Lout, par4, flags);
}

// Round 16
// 34.353 us; speedup vs baseline: 7.2399x; 7.2399x over previous
//
#include <hip/hip_runtime.h>
#include <math.h>

#define BB 4096
#define DD 1024
#define KK 5
#define PP 1323
#define PTS 7          // points per ptile; 1323 = 189 * 7
#define NPT 189        // p-tiles

// (2*pi)^(-3/2)
#define INV_2PI_POW15 0.06349363593424097f

// ---- head config ----
#define GR   16        // rows per head block -> 256 blocks
#define NWV  8         // waves per head block (512 threads)
#define HT   512       // head block threads
#define RST  13        // s_red inner stride (12 + 1)
#define CSTR 49        // s_c inner stride
#define NG   13        // param groups of 4
#define WPKN 49152     // packed weight elements

typedef short  bf16x8 __attribute__((ext_vector_type(8)));
typedef float  f32x4  __attribute__((ext_vector_type(4)));

__device__ __forceinline__ short f2bf(float f) {
    union { float f; unsigned u; } x; x.f = f;
    const unsigned r = x.u + 0x7fffu + ((x.u >> 16) & 1u);  // RNE
    return (short)(r >> 16);
}
__device__ __forceinline__ float softplus_f(float x) {
    return (x > 20.f) ? x : log1pf(expf(x));
}

__device__ __forceinline__ int wpk_index(int k, int j) {
    // Wpk[chunk][nt][lane][8]: k = chunk*32 + (lane>>4)*8 + ee, j = nt*16 + (lane&15)
    const int chunk = k >> 5;
    const int kin   = k & 31;
    const int lane  = ((kin >> 3) << 4) | (j & 15);
    const int nt    = j >> 4;
    const int ee    = k & 7;
    return ((chunk * 3 + nt) * 64 + lane) * 8 + ee;
}

// ---------------------------------------------------------------------------
// Kernel 0 (R10-identical): pack weights -> bf16 fragment order, coalesced.
// ---------------------------------------------------------------------------
__global__ __launch_bounds__(256) void pack_kernel(
    const float* __restrict__ Wmix,
    const float* __restrict__ Wmean,
    const float* __restrict__ Wscale,
    short* __restrict__ Wpk)
{
    const int e = blockIdx.x * 256 + threadIdx.x;   // 0 .. 49151
    int k, j; float v;
    if (e < 5120) {                       // Wmix: [1024][5]
        k = e / 5;  j = e - k * 5;
        v = Wmix[e];
    } else if (e < 17408) {               // Wmean: [1024][12]
        const int i = e - 5120;
        k = i / 12; j = 5 + (i - k * 12);
        v = Wmean[i];
    } else if (e < 48128) {               // Wscale: [1024][30]
        const int i = e - 17408;
        k = i / 30; j = 17 + (i - k * 30);
        v = Wscale[i];
    } else {                              // zero-fill j = 47
        k = e - 48128; j = 47; v = 0.f;
    }
    Wpk[wpk_index(k, j)] = f2bf(v);
}

// ---------------------------------------------------------------------------
// Kernel 1: fused head, 256 blocks x 512 thr (8 waves). Wave w = K-range
// [128w, 128w+128) = 4 chunks x 3 MFMAs. All 20 loads issued upfront (deep
// MLP); 8-deep LDS reduce (half of R10); (b,k) tail; coalesced Lout.
// ---------------------------------------------------------------------------
__global__ __launch_bounds__(HT, 2) void head_fused_kernel(
    const float* __restrict__ rep,
    const short* __restrict__ Wpk,
    const float* __restrict__ bmix,
    const float* __restrict__ bmean,
    const float* __restrict__ bscale,
    float* __restrict__ Lout,
    float* __restrict__ par4)
{
    __shared__ float s_red[NWV][64][RST];   // 26.6 KB
    __shared__ float s_c[GR][CSTR];         // 3.1 KB
    __shared__ float s_L[GR][KK][6];        // 1.9 KB

    const int t  = threadIdx.x;
    const int w  = t >> 6;          // wave 0..7
    const int l  = t & 63;
    const int lm = l & 15;
    const int lk = (l >> 4) * 8;
    const int b0 = blockIdx.x * GR;

    // ---- issue ALL loads upfront: 12 Wpk fragments + 8 rep f32x4 ----
    bf16x8 bh[4][3];
#pragma unroll
    for (int kt = 0; kt < 4; ++kt) {
        const int chunk = w * 4 + kt;
#pragma unroll
        for (int nt = 0; nt < 3; ++nt)
            bh[kt][nt] = *(const bf16x8*)(Wpk + (((size_t)chunk * 3 + nt) * 64 + l) * 8);
    }

    f32x4 a0[4], a1[4];
#pragma unroll
    for (int kt = 0; kt < 4; ++kt) {
        const int kof = (w * 4 + kt) * 32 + lk;
        const float* arow = rep + (size_t)(b0 + lm) * DD + kof;
        a0[kt] = *(const f32x4*)(arow);
        a1[kt] = *(const f32x4*)(arow + 4);
    }

    // ---- convert + MFMA ----
    f32x4 acc[3] = {f32x4{0,0,0,0}, f32x4{0,0,0,0}, f32x4{0,0,0,0}};
#pragma unroll
    for (int kt = 0; kt < 4; ++kt) {
        bf16x8 ah;
#pragma unroll
        for (int u = 0; u < 4; ++u) {
            ah[u]     = f2bf(a0[kt][u]);
            ah[u + 4] = f2bf(a1[kt][u]);
        }
#pragma unroll
        for (int nt = 0; nt < 3; ++nt)
            acc[nt] = __builtin_amdgcn_mfma_f32_16x16x32_bf16(ah, bh[kt][nt], acc[nt], 0, 0, 0);
    }

    // ---- 8-deep cross-wave reduce via LDS ----
#pragma unroll
    for (int nt = 0; nt < 3; ++nt)
#pragma unroll
        for (int r = 0; r < 4; ++r)
            s_red[w][l][nt * 4 + r] = acc[nt][r];
    __syncthreads();

    // cooperative sum into s_c[b_loc][j]; C layout [m89]:
    // col(=j) = lane&15, row(=b_loc) = (lane>>4)*4 + reg
    for (int e = t; e < GR * 47; e += HT) {
        const int b_loc = e & 15;
        const int j     = e >> 4;
        const int lane  = ((b_loc >> 2) << 4) | (j & 15);
        const int reg   = ((j >> 4) << 2) | (b_loc & 3);
        float s = 0.f;
#pragma unroll
        for (int q = 0; q < NWV; ++q) s += s_red[q][lane][reg];
        s_c[b_loc][j] = s;
    }
    __syncthreads();

    // ---- tail: 80 threads = 16 b x 5 k ----
    if (t < GR * KK) {
        const int k     = t >> 4;
        const int b_loc = t & 15;
        const int b     = b0 + b_loc;

        float logits[KK];
#pragma unroll
        for (int kk = 0; kk < KK; ++kk) logits[kk] = s_c[b_loc][kk] + bmix[kk];

        float m[3];
#pragma unroll
        for (int c = 0; c < 3; ++c)
            m[c] = (k > 0) ? (s_c[b_loc][5 + (k - 1) * 3 + c] + bmean[(k - 1) * 3 + c]) : 0.f;

        float sc[6];
#pragma unroll
        for (int c = 0; c < 6; ++c)
            sc[c] = s_c[b_loc][17 + k * 6 + c] + bscale[k * 6 + c];

        float mx = logits[0];
#pragma unroll
        for (int kk = 1; kk < KK; ++kk) mx = fmaxf(mx, logits[kk]);
        float den = 0.f;
#pragma unroll
        for (int kk = 0; kk < KK; ++kk) den += expf(logits[kk] - mx);
        const float wgt = expf(logits[k] - mx) / den;

        const float L00 = softplus_f(sc[0]);
        const float L10 = sc[1];
        const float L11 = softplus_f(sc[2]);
        const float L20 = sc[3];
        const float L21 = sc[4];
        const float L22 = softplus_f(sc[5]);

        const float r00 = 1.f / L00;
        const float r11 = 1.f / L11;
        const float r22 = 1.f / L22;
        const float a   = wgt * r00 * r11 * r22 * INV_2PI_POW15;

        s_L[b_loc][k][0] = L00;
        s_L[b_loc][k][1] = L10;
        s_L[b_loc][k][2] = L11;
        s_L[b_loc][k][3] = L20;
        s_L[b_loc][k][4] = L21;
        s_L[b_loc][k][5] = L22;

        // packed param store: q = k*10 + i -> par4[(q>>2)*BB + b][q&3]
        float pv[10] = { m[0], m[1], m[2], r00, L10, r11, L20, L21, r22, a };
#pragma unroll
        for (int i = 0; i < 10; ++i) {
            const int q = k * 10 + i;
            par4[(((size_t)(q >> 2)) * BB + b) * 4 + (q & 3)] = pv[i];
        }
    }
    __syncthreads();

    // ---- coalesced Lout write: 720 contiguous floats ----
    for (int e = t; e < GR * KK * 9; e += HT) {
        const int b_loc = e / 45;
        const int rem   = e - b_loc * 45;
        const int k     = rem / 9;
        const int e9    = rem - k * 9;
        const int rr    = e9 / 3;
        const int cc    = e9 - rr * 3;
        const float v = (cc > rr) ? 0.f : s_L[b_loc][k][(rr * (rr + 1)) / 2 + cc];
        Lout[(size_t)b0 * 45 + e] = v;
    }
}

// ---------------------------------------------------------------------------
// Kernel 2 (R10-identical): eval, PTS=7, par4 packed loads.
// ---------------------------------------------------------------------------
__global__ __launch_bounds__(256) void eval_kernel(
    const float* __restrict__ dxyz,
    const float* __restrict__ par4,
    float* __restrict__ out)
{
    const int b = blockIdx.x * 256 + threadIdx.x;

    float pr[NG * 4];
#pragma unroll
    for (int g = 0; g < NG; ++g) {
        const f32x4 v = *(const f32x4*)(par4 + ((size_t)g * BB + b) * 4);
        pr[g * 4 + 0] = v[0];
        pr[g * 4 + 1] = v[1];
        pr[g * 4 + 2] = v[2];
        pr[g * 4 + 3] = v[3];
    }

    const int p0 = blockIdx.y * PTS;
#pragma unroll
    for (int i = 0; i < PTS; ++i) {
        const int p = p0 + i;
        const size_t idx = (size_t)p * BB + b;
        const float* xv = dxyz + idx * 3;
        const float x0 = xv[0];
        const float x1 = xv[1];
        const float x2 = xv[2];

        float res = 0.f;
#pragma unroll
        for (int k = 0; k < KK; ++k) {
            const float d0 = x0 - pr[k * 10 + 0];
            const float d1 = x1 - pr[k * 10 + 1];
            const float d2 = x2 - pr[k * 10 + 2];
            const float z0 = d0 * pr[k * 10 + 3];
            const float z1 = fmaf(-pr[k * 10 + 4], z0, d1) * pr[k * 10 + 5];
            const float z2 = fmaf(-pr[k * 10 + 7], z1, fmaf(-pr[k * 10 + 6], z0, d2)) * pr[k * 10 + 8];
            const float q  = fmaf(z2, z2, fmaf(z1, z1, z0 * z0));
            res = fmaf(pr[k * 10 + 9], __expf(-0.5f * q), res);
        }
        out[idx] = res;
    }
}

extern "C" void kernel_launch(void* const* d_in, const int* in_sizes, int n_in,
                              void* d_out, int out_size, void* d_ws, size_t ws_size,
                              hipStream_t stream) {
    const float* rep    = (const float*)d_in[0];
    const float* dxyz   = (const float*)d_in[1];
    const float* Wmix   = (const float*)d_in[2];
    const float* bmix   = (const float*)d_in[3];
    const float* Wmean  = (const float*)d_in[4];
    const float* bmean  = (const float*)d_in[5];
    const float* Wscale = (const float*)d_in[6];
    const float* bscale = (const float*)d_in[7];

    float* out  = (float*)d_out;
    float* Lout = out + (size_t)BB * PP;          // second tuple output

    float* par4 = (float*)d_ws;                   // NG*BB*4 f32 (852 KB)
    short* Wpk  = (short*)(par4 + (size_t)NG * BB * 4);  // 49152 bf16 (98 KB)

    pack_kernel<<<192, 256, 0, stream>>>(Wmix, Wmean, Wscale, Wpk);

    head_fused_kernel<<<BB / GR, HT, 0, stream>>>(rep, Wpk, bmix, bmean, bscale, Lout, par4);

    eval_kernel<<<dim3(BB / 256, NPT), 256, 0, stream>>>(dxyz, par4, out);
}